// Round 1
// baseline (215.602 us; speedup 1.0000x reference)
//
#include <hip/hip_runtime.h>
#include <stdint.h>

// Problem: BS=8, N=2048, D=512
// out[b,i,d] = sigmoid(q)[b,i,d] * (eB @ (ek*v)) / (eB @ ek)
#define N_SEQ 2048
#define D_MODEL 512
#define MROWS 16384   // BS*N
#define XCOLS 8192    // BS * 2 * D  (interleaved num/den columns)

typedef __attribute__((ext_vector_type(8))) short bf16x8;
typedef __attribute__((ext_vector_type(4))) float f32x4;

__device__ __forceinline__ short f2bf(float f) {
  union { float f; uint32_t u; } x; x.f = f;
  uint32_t r = x.u + 0x7FFFu + ((x.u >> 16) & 1u);
  return (short)(uint16_t)(r >> 16);
}
__device__ __forceinline__ float bf2f(short s) {
  union { uint32_t u; float f; } x; x.u = ((uint32_t)(uint16_t)s) << 16;
  return x.f;
}

__device__ __forceinline__ void gload_lds16(const void* g, void* l) {
  __builtin_amdgcn_global_load_lds(
      (__attribute__((address_space(1))) void*)(void*)g,
      (__attribute__((address_space(3))) void*)l, 16, 0, 0);
}

// ---------------- prep kernels ----------------

// input fp32 -> bf16 hi + bf16 lo (residual)
__global__ void k_split_input(const float* __restrict__ in,
                              short* __restrict__ ah, short* __restrict__ al,
                              int n4) {
  int stride = gridDim.x * blockDim.x;
  for (int i = blockIdx.x * blockDim.x + threadIdx.x; i < n4; i += stride) {
    float4 v = reinterpret_cast<const float4*>(in)[i];
    short4 h, l;
    h.x = f2bf(v.x); l.x = f2bf(v.x - bf2f(h.x));
    h.y = f2bf(v.y); l.y = f2bf(v.y - bf2f(h.y));
    h.z = f2bf(v.z); l.z = f2bf(v.z - bf2f(h.z));
    h.w = f2bf(v.w); l.w = f2bf(v.w - bf2f(h.w));
    reinterpret_cast<short4*>(ah)[i] = h;
    reinterpret_cast<short4*>(al)[i] = l;
  }
}

// eB = bf16(exp(pos_bias))
__global__ void k_prep_eb(const float* __restrict__ pb, short* __restrict__ eb,
                          int n4) {
  int stride = gridDim.x * blockDim.x;
  for (int i = blockIdx.x * blockDim.x + threadIdx.x; i < n4; i += stride) {
    float4 v = reinterpret_cast<const float4*>(pb)[i];
    short4 o;
    o.x = f2bf(expf(v.x));
    o.y = f2bf(expf(v.y));
    o.z = f2bf(expf(v.z));
    o.w = f2bf(expf(v.w));
    reinterpret_cast<short4*>(eb)[i] = o;
  }
}

// Wt[c][k] hi/lo, col-major over k.  c<512: Wq col c; c>=512: c=512+2d+s,
// s=0 -> Wk col d, s=1 -> Wv col d   (k/v interleaved so lane pairs match)
__global__ void k_prep_w(const float* __restrict__ Wq, const float* __restrict__ Wk,
                         const float* __restrict__ Wv,
                         short* __restrict__ wh, short* __restrict__ wl) {
  int t = blockIdx.x * blockDim.x + threadIdx.x;
  if (t >= 1536 * 512) return;
  int c = t >> 9, k = t & 511;
  float v;
  if (c < 512) v = Wq[k * 512 + c];
  else {
    int cc = c - 512, d = cc >> 1;
    v = (cc & 1) ? Wv[k * 512 + d] : Wk[k * 512 + d];
  }
  short h = f2bf(v);
  wh[t] = h;
  wl[t] = f2bf(v - bf2f(h));
}

// ---------------- projection GEMM ----------------
// C(16384 x 1536) = A(16384 x 512) @ W(512 x 1536), split-bf16 (3 MFMA terms).
// 128x128 tile, BK=32, 4 waves (2x2), 16x16x32 MFMA.
// LDS tiles are [128][32] bf16 with paired-row XOR swizzle (2-way conflicts).
__global__ __launch_bounds__(256) void k_proj(
    const short* __restrict__ Ah, const short* __restrict__ Al,
    const short* __restrict__ Wh, const short* __restrict__ Wl,
    const float* __restrict__ bq, const float* __restrict__ bk,
    const float* __restrict__ bv,
    float* __restrict__ sig_out, short* __restrict__ Xt) {
  __shared__ short lAh[128 * 32], lAl[128 * 32], lWh[128 * 32], lWl[128 * 32];
  const int tid = threadIdx.x;
  const int lane = tid & 63, wid = tid >> 6;
  const int wr = wid >> 1, wc = wid & 1;
  const int lrow = lane & 15;
  const int koffb = (lane >> 4) << 4;  // byte offset of this lane's 8 k-elems
  const int row0 = blockIdx.x * 128;
  const int col0 = blockIdx.y * 128;

  const f32x4 fzero = {0.f, 0.f, 0.f, 0.f};
  f32x4 acc[4][4];
#pragma unroll
  for (int m = 0; m < 4; ++m)
#pragma unroll
    for (int n = 0; n < 4; ++n) acc[m][n] = fzero;

  const short* gAh = Ah + row0 * 512;
  const short* gAl = Al + row0 * 512;
  const short* gWh = Wh + col0 * 512;
  const short* gWl = Wl + col0 * 512;

  for (int kt = 0; kt < 16; ++kt) {
    const int kb = kt * 32;
    // stage: linear LDS dest, inverse-swizzled global source (rule 21)
#pragma unroll
    for (int p = 0; p < 2; ++p) {
      int c = p * 256 + tid;
      int B = c << 4;
      int r2 = B >> 7;
      int wp = (B & 127) ^ ((r2 & 7) << 4);
      int r = 2 * r2 + (wp >> 6);
      int ke = (wp & 63) >> 1;
      int goff = r * 512 + kb + ke;
      int loff = (p * 256 + wid * 64) << 3;  // wave-uniform chunk base (shorts)
      gload_lds16(gAh + goff, lAh + loff);
      gload_lds16(gAl + goff, lAl + loff);
      gload_lds16(gWh + goff, lWh + loff);
      gload_lds16(gWl + goff, lWl + loff);
    }
    __syncthreads();
    bf16x8 fwh[4], fwl[4];
#pragma unroll
    for (int n = 0; n < 4; ++n) {
      int r = wc * 64 + n * 16 + lrow;
      int off = ((r >> 1) << 7) +
                ((((r & 1) << 6) + koffb) ^ (((r >> 1) & 7) << 4));
      fwh[n] = *(const bf16x8*)((const char*)lWh + off);
      fwl[n] = *(const bf16x8*)((const char*)lWl + off);
    }
#pragma unroll
    for (int m = 0; m < 4; ++m) {
      int r = wr * 64 + m * 16 + lrow;
      int off = ((r >> 1) << 7) +
                ((((r & 1) << 6) + koffb) ^ (((r >> 1) & 7) << 4));
      bf16x8 fah = *(const bf16x8*)((const char*)lAh + off);
      bf16x8 fal = *(const bf16x8*)((const char*)lAl + off);
#pragma unroll
      for (int n = 0; n < 4; ++n) {
        acc[m][n] = __builtin_amdgcn_mfma_f32_16x16x32_bf16(fah, fwh[n], acc[m][n], 0, 0, 0);
        acc[m][n] = __builtin_amdgcn_mfma_f32_16x16x32_bf16(fah, fwl[n], acc[m][n], 0, 0, 0);
        acc[m][n] = __builtin_amdgcn_mfma_f32_16x16x32_bf16(fal, fwh[n], acc[m][n], 0, 0, 0);
      }
    }
    __syncthreads();
  }

  // epilogue.  C/D frag: col = lane&15, row = (lane>>4)*4 + reg
  const int rbase = row0 + wr * 64 + ((lane >> 4) << 2);
  if (col0 < 512) {  // q block: write sigmoid(q+bq) into d_out
#pragma unroll
    for (int n = 0; n < 4; ++n) {
      int c = col0 + wc * 64 + n * 16 + lrow;
      float bias = bq[c];
#pragma unroll
      for (int m = 0; m < 4; ++m) {
        int gr = rbase + m * 16;
#pragma unroll
        for (int r = 0; r < 4; ++r) {
          float q = acc[m][n][r] + bias;
          sig_out[(gr + r) * 512 + c] = 1.f / (1.f + expf(-q));
        }
      }
    }
  } else {  // k/v block: even lane holds k-col, odd lane holds v-col (same d)
    int s = lane & 1;
#pragma unroll
    for (int n = 0; n < 4; ++n) {
      int c = col0 + wc * 64 + n * 16 + lrow;
      int d = (c - 512) >> 1;
      float bias = s ? bv[d] : bk[d];
#pragma unroll
      for (int m = 0; m < 4; ++m) {
        int gr = rbase + m * 16;
        int b = gr >> 11;
        int j = gr & 2047;
        f32x4 val;
#pragma unroll
        for (int r = 0; r < 4; ++r) val[r] = acc[m][n][r] + bias;
        if (!s) {
#pragma unroll
          for (int r = 0; r < 4; ++r) val[r] = expf(val[r]);  // ek
        }
        f32x4 oth;
#pragma unroll
        for (int r = 0; r < 4; ++r) oth[r] = __shfl_xor(val[r], 1);
        if (!s) {  // even lane: val=ek, oth=v -> write w=ek*v and ek
          short4 wq, eq;
          wq.x = f2bf(val[0] * oth[0]); eq.x = f2bf(val[0]);
          wq.y = f2bf(val[1] * oth[1]); eq.y = f2bf(val[1]);
          wq.z = f2bf(val[2] * oth[2]); eq.z = f2bf(val[2]);
          wq.w = f2bf(val[3] * oth[3]); eq.w = f2bf(val[3]);
          int colp = b * 1024 + 2 * d;          // Xt transposed: [col][j]
          *(short4*)&Xt[colp * 2048 + j] = wq;  // num operand
          *(short4*)&Xt[(colp + 1) * 2048 + j] = eq;  // den operand
        }
      }
    }
  }
}

// ---------------- main GEMM ----------------
// out2(2048 x 8192) = eB(2048 x 2048) @ X(2048 x 8192); X given transposed
// (Xt[col][j]).  128x128 tile, BK=64, [128][64] bf16 LDS with XOR swizzle.
// Epilogue: pair num/den lanes via shfl, out = sigq * num/den (in-place d_out).
__global__ __launch_bounds__(256) void k_main(
    const short* __restrict__ eB, const short* __restrict__ Xt,
    float* __restrict__ io) {
  __shared__ short lA[128 * 64], lB[128 * 64];
  const int tid = threadIdx.x;
  const int lane = tid & 63, wid = tid >> 6;
  const int wr = wid >> 1, wc = wid & 1;
  const int lrow = lane & 15;
  const int kq = (lane >> 4) << 4;
  const int row0 = blockIdx.x * 128;
  const int col0 = blockIdx.y * 128;

  const f32x4 fzero = {0.f, 0.f, 0.f, 0.f};
  f32x4 acc[4][4];
#pragma unroll
  for (int m = 0; m < 4; ++m)
#pragma unroll
    for (int n = 0; n < 4; ++n) acc[m][n] = fzero;

  const short* gA = eB + row0 * 2048;
  const short* gB = Xt + col0 * 2048;

  for (int kt = 0; kt < 32; ++kt) {
    const int kb = kt * 64;
#pragma unroll
    for (int p = 0; p < 4; ++p) {
      int c = p * 256 + tid;
      int B = c << 4;
      int r = B >> 7;
      int wp = (B & 127) ^ ((r & 7) << 4);
      int ke = wp >> 1;
      int goff = r * 2048 + kb + ke;
      int loff = (p * 256 + wid * 64) << 3;
      gload_lds16(gA + goff, lA + loff);
      gload_lds16(gB + goff, lB + loff);
    }
    __syncthreads();
#pragma unroll
    for (int ks = 0; ks < 2; ++ks) {
      int kb2 = kq + ks * 64;
      bf16x8 fb[4];
#pragma unroll
      for (int n = 0; n < 4; ++n) {
        int r = wc * 64 + n * 16 + lrow;
        fb[n] = *(const bf16x8*)((const char*)lB + (r << 7) +
                                 (kb2 ^ ((r & 7) << 4)));
      }
#pragma unroll
      for (int m = 0; m < 4; ++m) {
        int r = wr * 64 + m * 16 + lrow;
        bf16x8 fa = *(const bf16x8*)((const char*)lA + (r << 7) +
                                     (kb2 ^ ((r & 7) << 4)));
#pragma unroll
        for (int n = 0; n < 4; ++n)
          acc[m][n] = __builtin_amdgcn_mfma_f32_16x16x32_bf16(fa, fb[n], acc[m][n], 0, 0, 0);
      }
    }
    __syncthreads();
  }

  const int rbase = row0 + wr * 64 + ((lane >> 4) << 2);
#pragma unroll
  for (int n = 0; n < 4; ++n) {
    int c = col0 + wc * 64 + n * 16 + lrow;
    int b = c >> 10;
    int d = (c & 1023) >> 1;
#pragma unroll
    for (int m = 0; m < 4; ++m) {
      f32x4 den;
#pragma unroll
      for (int r = 0; r < 4; ++r) den[r] = __shfl_xor(acc[m][n][r], 1);
      if ((lane & 1) == 0) {  // even lane: acc=num, den from odd partner
#pragma unroll
        for (int r = 0; r < 4; ++r) {
          int i = rbase + m * 16 + r;
          int idx = (b * 2048 + i) * 512 + d;
          float sg = io[idx];  // sigmoid(q) written by k_proj
          io[idx] = sg * (acc[m][n][r] / den[r]);
        }
      }
    }
  }
}

// ---------------- launch ----------------
extern "C" void kernel_launch(void* const* d_in, const int* in_sizes, int n_in,
                              void* d_out, int out_size, void* d_ws, size_t ws_size,
                              hipStream_t stream) {
  const float* in = (const float*)d_in[0];
  const float* Wq = (const float*)d_in[1];
  const float* bq = (const float*)d_in[2];
  const float* Wk = (const float*)d_in[3];
  const float* bk = (const float*)d_in[4];
  const float* Wv = (const float*)d_in[5];
  const float* bv = (const float*)d_in[6];
  const float* pb = (const float*)d_in[7];
  float* out = (float*)d_out;

  char* ws = (char*)d_ws;
  short* Xt = (short*)ws;                       // 8192*2048*2 = 33,554,432
  short* eB = (short*)(ws + 33554432);          //  8,388,608
  short* Ah = (short*)(ws + 41943040);          // 16,777,216
  short* Al = (short*)(ws + 58720256);          // 16,777,216
  short* Wh = (short*)(ws + 75497472);          //  1,572,864
  short* Wl = (short*)(ws + 77070336);          //  1,572,864 (end 78,643,200)

  k_split_input<<<2048, 256, 0, stream>>>(in, Ah, Al, MROWS * D_MODEL / 4);
  k_prep_w<<<3072, 256, 0, stream>>>(Wq, Wk, Wv, Wh, Wl);
  k_prep_eb<<<2048, 256, 0, stream>>>(pb, eB, N_SEQ * N_SEQ / 4);

  dim3 gp(128, 12);
  k_proj<<<gp, 256, 0, stream>>>(Ah, Al, Wh, Wl, bq, bk, bv, out, Xt);

  dim3 gm(16, 64);
  k_main<<<gm, 256, 0, stream>>>(eB, Xt, out);
}

// Round 2
// 164.392 us; speedup vs baseline: 1.3115x; 1.3115x over previous
//
#include <hip/hip_runtime.h>
#include <stdint.h>

// Problem: BS=8, N=2048, D=512
// out[b,i,d] = sigmoid(q)[b,i,d] * (eB @ (ek*v)) / (eB @ ek)
#define N_SEQ 2048
#define D_MODEL 512
#define MROWS 16384   // BS*N
#define XCOLS 8192    // BS * 2 * D  (interleaved num/den columns)

typedef __attribute__((ext_vector_type(8))) short bf16x8;
typedef __attribute__((ext_vector_type(4))) float f32x4;

__device__ __forceinline__ short f2bf(float f) {
  union { float f; uint32_t u; } x; x.f = f;
  uint32_t r = x.u + 0x7FFFu + ((x.u >> 16) & 1u);
  return (short)(uint16_t)(r >> 16);
}
__device__ __forceinline__ unsigned short f2h(float f) {
  union { _Float16 h; unsigned short u; } x; x.h = (_Float16)f; return x.u;
}
__device__ __forceinline__ float h2f(unsigned short u) {
  union { unsigned short u; _Float16 h; } x; x.u = u; return (float)x.h;
}

__device__ __forceinline__ void gload_lds16(const void* g, void* l) {
  __builtin_amdgcn_global_load_lds(
      (__attribute__((address_space(1))) void*)(void*)g,
      (__attribute__((address_space(3))) void*)l, 16, 0, 0);
}

// ---------------- prep kernels ----------------

// input fp32 -> bf16
__global__ void k_conv_bf16(const float* __restrict__ in,
                            short* __restrict__ a, int n4) {
  int stride = gridDim.x * blockDim.x;
  for (int i = blockIdx.x * blockDim.x + threadIdx.x; i < n4; i += stride) {
    float4 v = reinterpret_cast<const float4*>(in)[i];
    short4 h;
    h.x = f2bf(v.x); h.y = f2bf(v.y); h.z = f2bf(v.z); h.w = f2bf(v.w);
    reinterpret_cast<short4*>(a)[i] = h;
  }
}

// eB = bf16(exp(pos_bias))
__global__ void k_prep_eb(const float* __restrict__ pb, short* __restrict__ eb,
                          int n4) {
  int stride = gridDim.x * blockDim.x;
  for (int i = blockIdx.x * blockDim.x + threadIdx.x; i < n4; i += stride) {
    float4 v = reinterpret_cast<const float4*>(pb)[i];
    short4 o;
    o.x = f2bf(expf(v.x));
    o.y = f2bf(expf(v.y));
    o.z = f2bf(expf(v.z));
    o.w = f2bf(expf(v.w));
    reinterpret_cast<short4*>(eb)[i] = o;
  }
}

// Wt[c][k] bf16, col-major over k.  c<512: Wq col c; c>=512: c=512+2d+s,
// s=0 -> Wk col d, s=1 -> Wv col d   (k/v interleaved so lane pairs match)
__global__ void k_prep_w(const float* __restrict__ Wq, const float* __restrict__ Wk,
                         const float* __restrict__ Wv, short* __restrict__ wh) {
  int t = blockIdx.x * blockDim.x + threadIdx.x;
  if (t >= 1536 * 512) return;
  int c = t >> 9, k = t & 511;
  float v;
  if (c < 512) v = Wq[k * 512 + c];
  else {
    int cc = c - 512, d = cc >> 1;
    v = (cc & 1) ? Wv[k * 512 + d] : Wk[k * 512 + d];
  }
  wh[t] = f2bf(v);
}

// ---------------- projection GEMM ----------------
// C(16384 x 1536) = A(16384 x 512) @ W(512 x 1536), plain bf16.
// 128x128 tile, BK=64, 4 waves (2x2), 16x16x32 MFMA, XOR-swizzled LDS.
__global__ __launch_bounds__(256) void k_proj(
    const short* __restrict__ A, const short* __restrict__ W,
    const float* __restrict__ bq, const float* __restrict__ bk,
    const float* __restrict__ bv,
    unsigned short* __restrict__ sigq, short* __restrict__ Xt) {
  __shared__ short lA[128 * 64], lB[128 * 64];
  const int tid = threadIdx.x;
  const int lane = tid & 63, wid = tid >> 6;
  const int wr = wid >> 1, wc = wid & 1;
  const int lrow = lane & 15;
  const int kq = (lane >> 4) << 4;  // byte offset of lane's 8 k-elems
  const int row0 = blockIdx.x * 128;
  const int col0 = blockIdx.y * 128;

  const f32x4 fzero = {0.f, 0.f, 0.f, 0.f};
  f32x4 acc[4][4];
#pragma unroll
  for (int m = 0; m < 4; ++m)
#pragma unroll
    for (int n = 0; n < 4; ++n) acc[m][n] = fzero;

  const short* gA = A + row0 * 512;
  const short* gB = W + col0 * 512;

  for (int kt = 0; kt < 8; ++kt) {
    const int kb = kt * 64;
#pragma unroll
    for (int p = 0; p < 4; ++p) {
      int c = p * 256 + tid;
      int B = c << 4;
      int r = B >> 7;
      int wp = (B & 127) ^ ((r & 7) << 4);
      int ke = wp >> 1;
      int goff = r * 512 + kb + ke;
      int loff = (p * 256 + wid * 64) << 3;
      gload_lds16(gA + goff, lA + loff);
      gload_lds16(gB + goff, lB + loff);
    }
    __syncthreads();
#pragma unroll
    for (int ks = 0; ks < 2; ++ks) {
      int kb2 = kq + ks * 64;
      bf16x8 fb[4];
#pragma unroll
      for (int n = 0; n < 4; ++n) {
        int r = wc * 64 + n * 16 + lrow;
        fb[n] = *(const bf16x8*)((const char*)lB + (r << 7) +
                                 (kb2 ^ ((r & 7) << 4)));
      }
#pragma unroll
      for (int m = 0; m < 4; ++m) {
        int r = wr * 64 + m * 16 + lrow;
        bf16x8 fa = *(const bf16x8*)((const char*)lA + (r << 7) +
                                     (kb2 ^ ((r & 7) << 4)));
#pragma unroll
        for (int n = 0; n < 4; ++n)
          acc[m][n] = __builtin_amdgcn_mfma_f32_16x16x32_bf16(fa, fb[n], acc[m][n], 0, 0, 0);
      }
    }
    __syncthreads();
  }

  // epilogue.  C/D frag: col = lane&15, row = (lane>>4)*4 + reg
  const int rbase = row0 + wr * 64 + ((lane >> 4) << 2);
  if (col0 < 512) {  // q block: write fp16 sigmoid(q+bq) into ws
#pragma unroll
    for (int n = 0; n < 4; ++n) {
      int c = col0 + wc * 64 + n * 16 + lrow;
      float bias = bq[c];
#pragma unroll
      for (int m = 0; m < 4; ++m) {
        int gr = rbase + m * 16;
#pragma unroll
        for (int r = 0; r < 4; ++r) {
          float q = acc[m][n][r] + bias;
          sigq[(gr + r) * 512 + c] = f2h(1.f / (1.f + expf(-q)));
        }
      }
    }
  } else {  // k/v block: even lane holds k-col, odd lane holds v-col (same d)
    int s = lane & 1;
#pragma unroll
    for (int n = 0; n < 4; ++n) {
      int c = col0 + wc * 64 + n * 16 + lrow;
      int d = (c - 512) >> 1;
      float bias = s ? bv[d] : bk[d];
#pragma unroll
      for (int m = 0; m < 4; ++m) {
        int gr = rbase + m * 16;
        int b = gr >> 11;
        int j = gr & 2047;
        f32x4 val;
#pragma unroll
        for (int r = 0; r < 4; ++r) val[r] = acc[m][n][r] + bias;
        if (!s) {
#pragma unroll
          for (int r = 0; r < 4; ++r) val[r] = expf(val[r]);  // ek
        }
        f32x4 oth;
#pragma unroll
        for (int r = 0; r < 4; ++r) oth[r] = __shfl_xor(val[r], 1);
        if (!s) {  // even lane: val=ek, oth=v -> write w=ek*v and ek
          short4 wq, eq;
          wq.x = f2bf(val[0] * oth[0]); eq.x = f2bf(val[0]);
          wq.y = f2bf(val[1] * oth[1]); eq.y = f2bf(val[1]);
          wq.z = f2bf(val[2] * oth[2]); eq.z = f2bf(val[2]);
          wq.w = f2bf(val[3] * oth[3]); eq.w = f2bf(val[3]);
          int colp = b * 1024 + 2 * d;          // Xt transposed: [col][j]
          *(short4*)&Xt[colp * 2048 + j] = wq;  // num operand
          *(short4*)&Xt[(colp + 1) * 2048 + j] = eq;  // den operand
        }
      }
    }
  }
}

// ---------------- main GEMM ----------------
// out2(2048 x 8192) = eB(2048 x 2048) @ X(2048 x 8192); X given transposed
// (Xt[col][j]).  128x128 tile, BK=64, [128][64] bf16 LDS with XOR swizzle.
// Epilogue: pair num/den lanes via shfl, out = sigq * num/den.
__global__ __launch_bounds__(256) void k_main(
    const short* __restrict__ eB, const short* __restrict__ Xt,
    const unsigned short* __restrict__ sigq, float* __restrict__ out) {
  __shared__ short lA[128 * 64], lB[128 * 64];
  const int tid = threadIdx.x;
  const int lane = tid & 63, wid = tid >> 6;
  const int wr = wid >> 1, wc = wid & 1;
  const int lrow = lane & 15;
  const int kq = (lane >> 4) << 4;
  const int row0 = blockIdx.x * 128;
  const int col0 = blockIdx.y * 128;

  const f32x4 fzero = {0.f, 0.f, 0.f, 0.f};
  f32x4 acc[4][4];
#pragma unroll
  for (int m = 0; m < 4; ++m)
#pragma unroll
    for (int n = 0; n < 4; ++n) acc[m][n] = fzero;

  const short* gA = eB + row0 * 2048;
  const short* gB = Xt + col0 * 2048;

  for (int kt = 0; kt < 32; ++kt) {
    const int kb = kt * 64;
#pragma unroll
    for (int p = 0; p < 4; ++p) {
      int c = p * 256 + tid;
      int B = c << 4;
      int r = B >> 7;
      int wp = (B & 127) ^ ((r & 7) << 4);
      int ke = wp >> 1;
      int goff = r * 2048 + kb + ke;
      int loff = (p * 256 + wid * 64) << 3;
      gload_lds16(gA + goff, lA + loff);
      gload_lds16(gB + goff, lB + loff);
    }
    __syncthreads();
#pragma unroll
    for (int ks = 0; ks < 2; ++ks) {
      int kb2 = kq + ks * 64;
      bf16x8 fb[4];
#pragma unroll
      for (int n = 0; n < 4; ++n) {
        int r = wc * 64 + n * 16 + lrow;
        fb[n] = *(const bf16x8*)((const char*)lB + (r << 7) +
                                 (kb2 ^ ((r & 7) << 4)));
      }
#pragma unroll
      for (int m = 0; m < 4; ++m) {
        int r = wr * 64 + m * 16 + lrow;
        bf16x8 fa = *(const bf16x8*)((const char*)lA + (r << 7) +
                                     (kb2 ^ ((r & 7) << 4)));
#pragma unroll
        for (int n = 0; n < 4; ++n)
          acc[m][n] = __builtin_amdgcn_mfma_f32_16x16x32_bf16(fa, fb[n], acc[m][n], 0, 0, 0);
      }
    }
    __syncthreads();
  }

  const int rbase = row0 + wr * 64 + ((lane >> 4) << 2);
#pragma unroll
  for (int n = 0; n < 4; ++n) {
    int c = col0 + wc * 64 + n * 16 + lrow;
    int b = c >> 10;
    int d = (c & 1023) >> 1;
#pragma unroll
    for (int m = 0; m < 4; ++m) {
      f32x4 den;
#pragma unroll
      for (int r = 0; r < 4; ++r) den[r] = __shfl_xor(acc[m][n][r], 1);
      if ((lane & 1) == 0) {  // even lane: acc=num, den from odd partner
#pragma unroll
        for (int r = 0; r < 4; ++r) {
          int i = rbase + m * 16 + r;
          int idx = (b * 2048 + i) * 512 + d;
          float sg = h2f(sigq[idx]);
          out[idx] = sg * (acc[m][n][r] / den[r]);
        }
      }
    }
  }
}

// ---------------- launch ----------------
extern "C" void kernel_launch(void* const* d_in, const int* in_sizes, int n_in,
                              void* d_out, int out_size, void* d_ws, size_t ws_size,
                              hipStream_t stream) {
  const float* in = (const float*)d_in[0];
  const float* Wq = (const float*)d_in[1];
  const float* bq = (const float*)d_in[2];
  const float* Wk = (const float*)d_in[3];
  const float* bk = (const float*)d_in[4];
  const float* Wv = (const float*)d_in[5];
  const float* bv = (const float*)d_in[6];
  const float* pb = (const float*)d_in[7];
  float* out = (float*)d_out;

  char* ws = (char*)d_ws;
  short* Xt = (short*)ws;                              // 33,554,432 B
  short* eB = (short*)(ws + 33554432);                 //  8,388,608 B
  short* Ah = (short*)(ws + 41943040);                 // 16,777,216 B
  short* Wh = (short*)(ws + 58720256);                 //  1,572,864 B
  unsigned short* sigq = (unsigned short*)(ws + 60293120);  // 16,777,216 B (end 77,070,336)

  k_conv_bf16<<<2048, 256, 0, stream>>>(in, Ah, MROWS * D_MODEL / 4);
  k_prep_w<<<3072, 256, 0, stream>>>(Wq, Wk, Wv, Wh);
  k_prep_eb<<<2048, 256, 0, stream>>>(pb, eB, N_SEQ * N_SEQ / 4);

  dim3 gp(128, 12);
  k_proj<<<gp, 256, 0, stream>>>(Ah, Wh, bq, bk, bv, sigq, Xt);

  dim3 gm(16, 64);
  k_main<<<gm, 256, 0, stream>>>(eB, Xt, sigq, out);
}

// Round 3
// 148.793 us; speedup vs baseline: 1.4490x; 1.1048x over previous
//
#include <hip/hip_runtime.h>
#include <stdint.h>

// Problem: BS=8, N=2048, D=512
// out[b,i,d] = sigmoid(q)[b,i,d] * (eB @ (ek*v)) / (eB @ ek)
#define N_SEQ 2048
#define D_MODEL 512
#define MROWS 16384   // BS*N
#define NT_K 32       // K-tiles (K=2048 / BK=64) in main GEMM

typedef __attribute__((ext_vector_type(8))) short bf16x8;
typedef __attribute__((ext_vector_type(4))) float f32x4;

__device__ __forceinline__ short f2bf(float f) {
  union { float f; uint32_t u; } x; x.f = f;
  uint32_t r = x.u + 0x7FFFu + ((x.u >> 16) & 1u);
  return (short)(uint16_t)(r >> 16);
}
__device__ __forceinline__ unsigned short f2h(float f) {
  union { _Float16 h; unsigned short u; } x; x.h = (_Float16)f; return x.u;
}
__device__ __forceinline__ float h2f(unsigned short u) {
  union { unsigned short u; _Float16 h; } x; x.u = u; return (float)x.h;
}

__device__ __forceinline__ void gload_lds16(const void* g, void* l) {
  __builtin_amdgcn_global_load_lds(
      (__attribute__((address_space(1))) void*)(void*)g,
      (__attribute__((address_space(3))) void*)l, 16, 0, 0);
}

// ---------------- prep kernels ----------------

__global__ void k_conv_bf16(const float* __restrict__ in,
                            short* __restrict__ a, int n4) {
  int stride = gridDim.x * blockDim.x;
  for (int i = blockIdx.x * blockDim.x + threadIdx.x; i < n4; i += stride) {
    float4 v = reinterpret_cast<const float4*>(in)[i];
    short4 h;
    h.x = f2bf(v.x); h.y = f2bf(v.y); h.z = f2bf(v.z); h.w = f2bf(v.w);
    reinterpret_cast<short4*>(a)[i] = h;
  }
}

__global__ void k_prep_eb(const float* __restrict__ pb, short* __restrict__ eb,
                          int n4) {
  int stride = gridDim.x * blockDim.x;
  for (int i = blockIdx.x * blockDim.x + threadIdx.x; i < n4; i += stride) {
    float4 v = reinterpret_cast<const float4*>(pb)[i];
    short4 o;
    o.x = f2bf(expf(v.x));
    o.y = f2bf(expf(v.y));
    o.z = f2bf(expf(v.z));
    o.w = f2bf(expf(v.w));
    reinterpret_cast<short4*>(eb)[i] = o;
  }
}

// Wt[c][k] bf16, col-major over k.  c<512: Wq col c; c>=512: c=512+2d+s,
// s=0 -> Wk col d, s=1 -> Wv col d
__global__ void k_prep_w(const float* __restrict__ Wq, const float* __restrict__ Wk,
                         const float* __restrict__ Wv, short* __restrict__ wh) {
  int t = blockIdx.x * blockDim.x + threadIdx.x;
  if (t >= 1536 * 512) return;
  int c = t >> 9, k = t & 511;
  float v;
  if (c < 512) v = Wq[k * 512 + c];
  else {
    int cc = c - 512, d = cc >> 1;
    v = (cc & 1) ? Wv[k * 512 + d] : Wk[k * 512 + d];
  }
  wh[t] = f2bf(v);
}

// ---------------- projection GEMM (128^2 2-phase, unchanged) ----------------
__global__ __launch_bounds__(256) void k_proj(
    const short* __restrict__ A, const short* __restrict__ W,
    const float* __restrict__ bq, const float* __restrict__ bk,
    const float* __restrict__ bv,
    unsigned short* __restrict__ sigq, short* __restrict__ Xt) {
  __shared__ short lA[128 * 64], lB[128 * 64];
  const int tid = threadIdx.x;
  const int lane = tid & 63, wid = tid >> 6;
  const int wr = wid >> 1, wc = wid & 1;
  const int lrow = lane & 15;
  const int kq = (lane >> 4) << 4;
  const int row0 = blockIdx.x * 128;
  const int col0 = blockIdx.y * 128;

  const f32x4 fzero = {0.f, 0.f, 0.f, 0.f};
  f32x4 acc[4][4];
#pragma unroll
  for (int m = 0; m < 4; ++m)
#pragma unroll
    for (int n = 0; n < 4; ++n) acc[m][n] = fzero;

  const short* gA = A + row0 * 512;
  const short* gB = W + col0 * 512;

  for (int kt = 0; kt < 8; ++kt) {
    const int kb = kt * 64;
#pragma unroll
    for (int p = 0; p < 4; ++p) {
      int c = p * 256 + tid;
      int B = c << 4;
      int r = B >> 7;
      int wp = (B & 127) ^ ((r & 7) << 4);
      int ke = wp >> 1;
      int goff = r * 512 + kb + ke;
      int loff = (p * 256 + wid * 64) << 3;
      gload_lds16(gA + goff, lA + loff);
      gload_lds16(gB + goff, lB + loff);
    }
    __syncthreads();
#pragma unroll
    for (int ks = 0; ks < 2; ++ks) {
      int kb2 = kq + ks * 64;
      bf16x8 fb[4];
#pragma unroll
      for (int n = 0; n < 4; ++n) {
        int r = wc * 64 + n * 16 + lrow;
        fb[n] = *(const bf16x8*)((const char*)lB + (r << 7) +
                                 (kb2 ^ ((r & 7) << 4)));
      }
#pragma unroll
      for (int m = 0; m < 4; ++m) {
        int r = wr * 64 + m * 16 + lrow;
        bf16x8 fa = *(const bf16x8*)((const char*)lA + (r << 7) +
                                     (kb2 ^ ((r & 7) << 4)));
#pragma unroll
        for (int n = 0; n < 4; ++n)
          acc[m][n] = __builtin_amdgcn_mfma_f32_16x16x32_bf16(fa, fb[n], acc[m][n], 0, 0, 0);
      }
    }
    __syncthreads();
  }

  const int rbase = row0 + wr * 64 + ((lane >> 4) << 2);
  if (col0 < 512) {
#pragma unroll
    for (int n = 0; n < 4; ++n) {
      int c = col0 + wc * 64 + n * 16 + lrow;
      float bias = bq[c];
#pragma unroll
      for (int m = 0; m < 4; ++m) {
        int gr = rbase + m * 16;
#pragma unroll
        for (int r = 0; r < 4; ++r) {
          float q = acc[m][n][r] + bias;
          sigq[(gr + r) * 512 + c] = f2h(1.f / (1.f + expf(-q)));
        }
      }
    }
  } else {
    int s = lane & 1;
#pragma unroll
    for (int n = 0; n < 4; ++n) {
      int c = col0 + wc * 64 + n * 16 + lrow;
      int d = (c - 512) >> 1;
      float bias = s ? bv[d] : bk[d];
#pragma unroll
      for (int m = 0; m < 4; ++m) {
        int gr = rbase + m * 16;
        int b = gr >> 11;
        int j = gr & 2047;
        f32x4 val;
#pragma unroll
        for (int r = 0; r < 4; ++r) val[r] = acc[m][n][r] + bias;
        if (!s) {
#pragma unroll
          for (int r = 0; r < 4; ++r) val[r] = expf(val[r]);
        }
        f32x4 oth;
#pragma unroll
        for (int r = 0; r < 4; ++r) oth[r] = __shfl_xor(val[r], 1);
        if (!s) {
          short4 wq, eq;
          wq.x = f2bf(val[0] * oth[0]); eq.x = f2bf(val[0]);
          wq.y = f2bf(val[1] * oth[1]); eq.y = f2bf(val[1]);
          wq.z = f2bf(val[2] * oth[2]); eq.z = f2bf(val[2]);
          wq.w = f2bf(val[3] * oth[3]); eq.w = f2bf(val[3]);
          int colp = b * 1024 + 2 * d;
          *(short4*)&Xt[colp * 2048 + j] = wq;
          *(short4*)&Xt[(colp + 1) * 2048 + j] = eq;
        }
      }
    }
  }
}

// ---------------- main GEMM: 256^2 tile, 8-phase counted-vmcnt ----------------
// out2(2048 x 8192) = eB(2048 x 2048) @ X(2048 x 8192), X K-major (Xt[col][j]).
// 512 thr = 8 waves (2M x 4N), per-wave 128x64 out.  BK=64, 2 K-tiles/iter.
// LDS 128KB = 2 bufs x (A 256x64 + B 256x64) bf16, XOR-swizzled rows.
// Phase p: {ds_read subtile | stage 1 half-tile | barrier | lgkm0 | 16 MFMA | barrier}
// vmcnt(4) at phases 3 and 7 only (2 half-tiles stay in flight).

#define MM(FA, FB, NH)                                                      \
  {                                                                         \
    _Pragma("unroll") for (int mm_ = 0; mm_ < 8; ++mm_) {                   \
      acc[mm_][2 * (NH)] = __builtin_amdgcn_mfma_f32_16x16x32_bf16(         \
          FA[mm_], FB[2 * (NH)], acc[mm_][2 * (NH)], 0, 0, 0);              \
      acc[mm_][2 * (NH) + 1] = __builtin_amdgcn_mfma_f32_16x16x32_bf16(     \
          FA[mm_], FB[2 * (NH) + 1], acc[mm_][2 * (NH) + 1], 0, 0, 0);      \
    }                                                                       \
  }

#define PHASE_MID()                                     \
  __builtin_amdgcn_sched_barrier(0);                    \
  __builtin_amdgcn_s_barrier();                         \
  asm volatile("s_waitcnt lgkmcnt(0)" ::: "memory");    \
  __builtin_amdgcn_sched_barrier(0);                    \
  __builtin_amdgcn_s_setprio(1)

#define PHASE_END()                                     \
  __builtin_amdgcn_s_setprio(0);                        \
  __builtin_amdgcn_sched_barrier(0);                    \
  __builtin_amdgcn_s_barrier()

#define VMCNT4() asm volatile("s_waitcnt vmcnt(4)" ::: "memory")

__global__ __launch_bounds__(512, 1) void k_main8(
    const short* __restrict__ eB, const short* __restrict__ Xt,
    const unsigned short* __restrict__ sigq, float* __restrict__ out) {
  extern __shared__ short lds[];  // 65536 shorts = 128 KB
  const int tid = threadIdx.x;
  const int lane = tid & 63, wid = tid >> 6;
  const int wr = wid >> 2, wc = wid & 3;
  const int lrow = lane & 15;
  const int khi = (lane >> 4) << 4;  // lane's k-byte suboffset within 64B
  const int row0 = blockIdx.x * 256;
  const int col0 = blockIdx.y * 256;

  const f32x4 fzero = {0.f, 0.f, 0.f, 0.f};
  f32x4 acc[8][4];
#pragma unroll
  for (int m = 0; m < 8; ++m)
#pragma unroll
    for (int n = 0; n < 4; ++n) acc[m][n] = fzero;

  const short* gA = eB + row0 * 2048;
  const short* gB = Xt + col0 * 2048;

  // stage one half-tile (128 rows x 64 k) = 2 x global_load_lds(16B)/thread.
  // Linear LDS dest, inverse-swizzled global source (rule 21).
  auto STAGE = [&](int kt, int isB, int h) {
    int ktc = kt < NT_K ? kt : NT_K - 1;  // clamp: keep vmcnt counts uniform
    const short* src = (isB ? gB : gA) + (h * 128) * 2048 + ktc * 64;
    int sbase = ((ktc & 1) << 15) + (isB << 14) + (h << 13);
#pragma unroll
    for (int p = 0; p < 2; ++p) {
      int c = p * 512 + tid;
      int r = c >> 3;
      int ke = ((((c & 7) << 4) ^ ((r & 7) << 4)) >> 1);
      gload_lds16(src + r * 2048 + ke,
                  lds + sbase + ((p * 512 + wid * 64) << 3));
    }
  };
  auto LDA = [&](int buf, int ks, int m) -> bf16x8 {
    int R = wr * 128 + m * 16 + lrow;
    int kb = ks * 64 + khi;
    return *(const bf16x8*)((const char*)lds + (buf << 16) + R * 128 +
                            (kb ^ ((R & 7) << 4)));
  };
  auto LDB = [&](int buf, int ks, int n) -> bf16x8 {
    int Rc = wc * 64 + n * 16 + lrow;
    int kb = ks * 64 + khi;
    return *(const bf16x8*)((const char*)lds + (buf << 16) + 32768 +
                            Rc * 128 + (kb ^ ((Rc & 7) << 4)));
  };

  // prologue: K-tile 0 (buf0) fully + K-tile 1 (buf1) A halves
  STAGE(0, 0, 0); STAGE(0, 0, 1); STAGE(0, 1, 0); STAGE(0, 1, 1);
  STAGE(1, 0, 0); STAGE(1, 0, 1);
  VMCNT4();  // first 8 loads (buf0) landed
  __builtin_amdgcn_sched_barrier(0);
  __builtin_amdgcn_s_barrier();

  bf16x8 fa0[8], fa1[8], fb0[4], fb1[4];

  for (int it = 0; it < NT_K / 2; ++it) {
    const int t0 = 2 * it, t1 = 2 * it + 1;
    // ph0: read t0/ks0 (12 reads); stage t1.B0; MFMA t0 ks0 nh0
#pragma unroll
    for (int m = 0; m < 8; ++m) fa0[m] = LDA(0, 0, m);
#pragma unroll
    for (int n = 0; n < 4; ++n) fb0[n] = LDB(0, 0, n);
    STAGE(t1, 1, 0);
    PHASE_MID();
    MM(fa0, fb0, 0);
    PHASE_END();
    // ph1: read t0/ks1; stage t1.B1; MFMA t0 ks0 nh1
#pragma unroll
    for (int m = 0; m < 8; ++m) fa1[m] = LDA(0, 1, m);
#pragma unroll
    for (int n = 0; n < 4; ++n) fb1[n] = LDB(0, 1, n);
    STAGE(t1, 1, 1);
    PHASE_MID();
    MM(fa0, fb0, 1);
    PHASE_END();
    // ph2: stage (t0+2).A0 (buf0 reads done after ph1); MFMA t0 ks1 nh0
    STAGE(t0 + 2, 0, 0);
    PHASE_MID();
    MM(fa1, fb1, 0);
    PHASE_END();
    // ph3: stage (t0+2).A1; vmcnt(4) -> buf1 (t1) fully landed; MFMA t0 ks1 nh1
    STAGE(t0 + 2, 0, 1);
    VMCNT4();
    PHASE_MID();
    MM(fa1, fb1, 1);
    PHASE_END();
    // ph4: read t1/ks0; stage (t0+2).B0; MFMA t1 ks0 nh0
#pragma unroll
    for (int m = 0; m < 8; ++m) fa0[m] = LDA(1, 0, m);
#pragma unroll
    for (int n = 0; n < 4; ++n) fb0[n] = LDB(1, 0, n);
    STAGE(t0 + 2, 1, 0);
    PHASE_MID();
    MM(fa0, fb0, 0);
    PHASE_END();
    // ph5: read t1/ks1; stage (t0+2).B1; MFMA t1 ks0 nh1
#pragma unroll
    for (int m = 0; m < 8; ++m) fa1[m] = LDA(1, 1, m);
#pragma unroll
    for (int n = 0; n < 4; ++n) fb1[n] = LDB(1, 1, n);
    STAGE(t0 + 2, 1, 1);
    PHASE_MID();
    MM(fa0, fb0, 1);
    PHASE_END();
    // ph6: stage (t1+2).A0 (buf1 reads done after ph5); MFMA t1 ks1 nh0
    STAGE(t1 + 2, 0, 0);
    PHASE_MID();
    MM(fa1, fb1, 0);
    PHASE_END();
    // ph7: stage (t1+2).A1; vmcnt(4) -> buf0 (t0+2) fully landed; MFMA t1 ks1 nh1
    STAGE(t1 + 2, 0, 1);
    VMCNT4();
    PHASE_MID();
    MM(fa1, fb1, 1);
    PHASE_END();
  }

  // epilogue: C/D frag col = lane&15, row = (lane>>4)*4 + reg
  const int rbase = row0 + wr * 128 + ((lane >> 4) << 2);
#pragma unroll
  for (int n = 0; n < 4; ++n) {
    int c = col0 + wc * 64 + n * 16 + lrow;
    int b = c >> 10;
    int d = (c & 1023) >> 1;
#pragma unroll
    for (int m = 0; m < 8; ++m) {
      f32x4 den;
#pragma unroll
      for (int r = 0; r < 4; ++r) den[r] = __shfl_xor(acc[m][n][r], 1);
      if ((lane & 1) == 0) {  // even lane: acc=num, partner holds den
#pragma unroll
        for (int r = 0; r < 4; ++r) {
          int i2 = rbase + m * 16 + r;
          int idx = (b * 2048 + i2) * 512 + d;
          out[idx] = h2f(sigq[idx]) * (acc[m][n][r] / den[r]);
        }
      }
    }
  }
}

// ---------------- launch ----------------
extern "C" void kernel_launch(void* const* d_in, const int* in_sizes, int n_in,
                              void* d_out, int out_size, void* d_ws, size_t ws_size,
                              hipStream_t stream) {
  const float* in = (const float*)d_in[0];
  const float* Wq = (const float*)d_in[1];
  const float* bq = (const float*)d_in[2];
  const float* Wk = (const float*)d_in[3];
  const float* bk = (const float*)d_in[4];
  const float* Wv = (const float*)d_in[5];
  const float* bv = (const float*)d_in[6];
  const float* pb = (const float*)d_in[7];
  float* out = (float*)d_out;

  char* ws = (char*)d_ws;
  short* Xt = (short*)ws;                              // 33,554,432 B
  short* eB = (short*)(ws + 33554432);                 //  8,388,608 B
  short* Ah = (short*)(ws + 41943040);                 // 16,777,216 B
  short* Wh = (short*)(ws + 58720256);                 //  1,572,864 B
  unsigned short* sigq = (unsigned short*)(ws + 60293120);  // 16,777,216 B

  (void)hipFuncSetAttribute((const void*)k_main8,
                            hipFuncAttributeMaxDynamicSharedMemorySize, 131072);

  k_conv_bf16<<<2048, 256, 0, stream>>>(in, Ah, MROWS * D_MODEL / 4);
  k_prep_w<<<3072, 256, 0, stream>>>(Wq, Wk, Wv, Wh);
  k_prep_eb<<<2048, 256, 0, stream>>>(pb, eB, N_SEQ * N_SEQ / 4);

  dim3 gp(128, 12);
  k_proj<<<gp, 256, 0, stream>>>(Ah, Wh, bq, bk, bv, sigq, Xt);

  dim3 gm(8, 32);
  k_main8<<<gm, 512, 131072, stream>>>(eB, Xt, sigq, out);
}

// Round 4
// 147.869 us; speedup vs baseline: 1.4581x; 1.0063x over previous
//
#include <hip/hip_runtime.h>
#include <stdint.h>

// Problem: BS=8, N=2048, D=512
// out[b,i,d] = sigmoid(q)[b,i,d] * (eB @ (ek*v)) / (eB @ ek)
#define N_SEQ 2048
#define D_MODEL 512
#define MROWS 16384   // BS*N
#define NT_K 32       // K-tiles (K=2048 / BK=64) in main GEMM

typedef __attribute__((ext_vector_type(8))) short bf16x8;
typedef __attribute__((ext_vector_type(4))) float f32x4;

__device__ __forceinline__ short f2bf(float f) {
  union { float f; uint32_t u; } x; x.f = f;
  uint32_t r = x.u + 0x7FFFu + ((x.u >> 16) & 1u);
  return (short)(uint16_t)(r >> 16);
}
__device__ __forceinline__ unsigned short f2h(float f) {
  union { _Float16 h; unsigned short u; } x; x.h = (_Float16)f; return x.u;
}
__device__ __forceinline__ float h2f(unsigned short u) {
  union { unsigned short u; _Float16 h; } x; x.u = u; return (float)x.h;
}

__device__ __forceinline__ void gload_lds16(const void* g, void* l) {
  __builtin_amdgcn_global_load_lds(
      (__attribute__((address_space(1))) void*)(void*)g,
      (__attribute__((address_space(3))) void*)l, 16, 0, 0);
}

// ---------------- prep kernels ----------------

__global__ void k_conv_bf16(const float* __restrict__ in,
                            short* __restrict__ a, int n4) {
  int stride = gridDim.x * blockDim.x;
  for (int i = blockIdx.x * blockDim.x + threadIdx.x; i < n4; i += stride) {
    float4 v = reinterpret_cast<const float4*>(in)[i];
    short4 h;
    h.x = f2bf(v.x); h.y = f2bf(v.y); h.z = f2bf(v.z); h.w = f2bf(v.w);
    reinterpret_cast<short4*>(a)[i] = h;
  }
}

__global__ void k_prep_eb(const float* __restrict__ pb, short* __restrict__ eb,
                          int n4) {
  int stride = gridDim.x * blockDim.x;
  for (int i = blockIdx.x * blockDim.x + threadIdx.x; i < n4; i += stride) {
    float4 v = reinterpret_cast<const float4*>(pb)[i];
    short4 o;
    o.x = f2bf(expf(v.x));
    o.y = f2bf(expf(v.y));
    o.z = f2bf(expf(v.z));
    o.w = f2bf(expf(v.w));
    reinterpret_cast<short4*>(eb)[i] = o;
  }
}

// Wt[c][k] bf16, col-major over k.  c<512: Wq col c; c>=512: c=512+2d+s,
// s=0 -> Wk col d, s=1 -> Wv col d
__global__ void k_prep_w(const float* __restrict__ Wq, const float* __restrict__ Wk,
                         const float* __restrict__ Wv, short* __restrict__ wh) {
  int t = blockIdx.x * blockDim.x + threadIdx.x;
  if (t >= 1536 * 512) return;
  int c = t >> 9, k = t & 511;
  float v;
  if (c < 512) v = Wq[k * 512 + c];
  else {
    int cc = c - 512, d = cc >> 1;
    v = (cc & 1) ? Wv[k * 512 + d] : Wk[k * 512 + d];
  }
  wh[t] = f2bf(v);
}

// ---------------- projection GEMM (128^2 2-phase, unchanged) ----------------
__global__ __launch_bounds__(256) void k_proj(
    const short* __restrict__ A, const short* __restrict__ W,
    const float* __restrict__ bq, const float* __restrict__ bk,
    const float* __restrict__ bv,
    unsigned short* __restrict__ sigq, short* __restrict__ Xt) {
  __shared__ short lA[128 * 64], lB[128 * 64];
  const int tid = threadIdx.x;
  const int lane = tid & 63, wid = tid >> 6;
  const int wr = wid >> 1, wc = wid & 1;
  const int lrow = lane & 15;
  const int kq = (lane >> 4) << 4;
  const int row0 = blockIdx.x * 128;
  const int col0 = blockIdx.y * 128;

  const f32x4 fzero = {0.f, 0.f, 0.f, 0.f};
  f32x4 acc[4][4];
#pragma unroll
  for (int m = 0; m < 4; ++m)
#pragma unroll
    for (int n = 0; n < 4; ++n) acc[m][n] = fzero;

  const short* gA = A + row0 * 512;
  const short* gB = W + col0 * 512;

  for (int kt = 0; kt < 8; ++kt) {
    const int kb = kt * 64;
#pragma unroll
    for (int p = 0; p < 4; ++p) {
      int c = p * 256 + tid;
      int B = c << 4;
      int r = B >> 7;
      int wp = (B & 127) ^ ((r & 7) << 4);
      int ke = wp >> 1;
      int goff = r * 512 + kb + ke;
      int loff = (p * 256 + wid * 64) << 3;
      gload_lds16(gA + goff, lA + loff);
      gload_lds16(gB + goff, lB + loff);
    }
    __syncthreads();
#pragma unroll
    for (int ks = 0; ks < 2; ++ks) {
      int kb2 = kq + ks * 64;
      bf16x8 fb[4];
#pragma unroll
      for (int n = 0; n < 4; ++n) {
        int r = wc * 64 + n * 16 + lrow;
        fb[n] = *(const bf16x8*)((const char*)lB + (r << 7) +
                                 (kb2 ^ ((r & 7) << 4)));
      }
#pragma unroll
      for (int m = 0; m < 4; ++m) {
        int r = wr * 64 + m * 16 + lrow;
        bf16x8 fa = *(const bf16x8*)((const char*)lA + (r << 7) +
                                     (kb2 ^ ((r & 7) << 4)));
#pragma unroll
        for (int n = 0; n < 4; ++n)
          acc[m][n] = __builtin_amdgcn_mfma_f32_16x16x32_bf16(fa, fb[n], acc[m][n], 0, 0, 0);
      }
    }
    __syncthreads();
  }

  const int rbase = row0 + wr * 64 + ((lane >> 4) << 2);
  if (col0 < 512) {
#pragma unroll
    for (int n = 0; n < 4; ++n) {
      int c = col0 + wc * 64 + n * 16 + lrow;
      float bias = bq[c];
#pragma unroll
      for (int m = 0; m < 4; ++m) {
        int gr = rbase + m * 16;
#pragma unroll
        for (int r = 0; r < 4; ++r) {
          float q = acc[m][n][r] + bias;
          sigq[(gr + r) * 512 + c] = f2h(1.f / (1.f + expf(-q)));
        }
      }
    }
  } else {
    int s = lane & 1;
#pragma unroll
    for (int n = 0; n < 4; ++n) {
      int c = col0 + wc * 64 + n * 16 + lrow;
      int d = (c - 512) >> 1;
      float bias = s ? bv[d] : bk[d];
#pragma unroll
      for (int m = 0; m < 4; ++m) {
        int gr = rbase + m * 16;
        int b = gr >> 11;
        int j = gr & 2047;
        f32x4 val;
#pragma unroll
        for (int r = 0; r < 4; ++r) val[r] = acc[m][n][r] + bias;
        if (!s) {
#pragma unroll
          for (int r = 0; r < 4; ++r) val[r] = expf(val[r]);
        }
        f32x4 oth;
#pragma unroll
        for (int r = 0; r < 4; ++r) oth[r] = __shfl_xor(val[r], 1);
        if (!s) {
          short4 wq, eq;
          wq.x = f2bf(val[0] * oth[0]); eq.x = f2bf(val[0]);
          wq.y = f2bf(val[1] * oth[1]); eq.y = f2bf(val[1]);
          wq.z = f2bf(val[2] * oth[2]); eq.z = f2bf(val[2]);
          wq.w = f2bf(val[3] * oth[3]); eq.w = f2bf(val[3]);
          int colp = b * 1024 + 2 * d;
          *(short4*)&Xt[colp * 2048 + j] = wq;
          *(short4*)&Xt[(colp + 1) * 2048 + j] = eq;
        }
      }
    }
  }
}

// ---------------- main GEMM: 256^2 tile, 8-phase counted-vmcnt ----------------
// out2(2048 x 8192) = eB(2048 x 2048) @ X(2048 x 8192), X K-major (Xt[col][j]).
// 512 thr = 8 waves (2M x 4N), per-wave 128x64 out.  BK=64, 2 K-tiles/iter.
// LDS 128KB = 2 bufs x (A 256x64 + B 256x64) bf16, XOR-swizzled rows.
// XCD-chunk swizzle: each XCD gets an 8-row x 4-col rectangle of tiles so its
// L2 fetches 8 A-panels + 4 B-panels (12 MB) instead of 32 B-panels.

#define MM(FA, FB, NH)                                                      \
  {                                                                         \
    _Pragma("unroll") for (int mm_ = 0; mm_ < 8; ++mm_) {                   \
      acc[mm_][2 * (NH)] = __builtin_amdgcn_mfma_f32_16x16x32_bf16(         \
          FA[mm_], FB[2 * (NH)], acc[mm_][2 * (NH)], 0, 0, 0);              \
      acc[mm_][2 * (NH) + 1] = __builtin_amdgcn_mfma_f32_16x16x32_bf16(     \
          FA[mm_], FB[2 * (NH) + 1], acc[mm_][2 * (NH) + 1], 0, 0, 0);      \
    }                                                                       \
  }

#define PHASE_MID()                                     \
  __builtin_amdgcn_sched_barrier(0);                    \
  __builtin_amdgcn_s_barrier();                         \
  asm volatile("s_waitcnt lgkmcnt(0)" ::: "memory");    \
  __builtin_amdgcn_sched_barrier(0);                    \
  __builtin_amdgcn_s_setprio(1)

#define PHASE_END()                                     \
  __builtin_amdgcn_s_setprio(0);                        \
  __builtin_amdgcn_sched_barrier(0);                    \
  __builtin_amdgcn_s_barrier()

#define VMCNT4() asm volatile("s_waitcnt vmcnt(4)" ::: "memory")

__global__ __launch_bounds__(512, 1) void k_main8(
    const short* __restrict__ eB, const short* __restrict__ Xt,
    const unsigned short* __restrict__ sigq, float* __restrict__ out) {
  extern __shared__ short lds[];  // 65536 shorts = 128 KB
  const int tid = threadIdx.x;
  const int lane = tid & 63, wid = tid >> 6;
  const int wr = wid >> 2, wc = wid & 3;
  const int lrow = lane & 15;
  const int khi = (lane >> 4) << 4;  // lane's k-byte suboffset within 64B

  // XCD-chunk swizzle (bijective, 256 blocks, assumes xcd = id % 8):
  // xcd c gets rows 0..7 x cols 4c..4c+3.
  const int bid = blockIdx.x;
  const int xcd = bid & 7, j = bid >> 3;
  const int row0 = (j & 7) * 256;
  const int col0 = ((xcd << 2) + (j >> 3)) * 256;

  const f32x4 fzero = {0.f, 0.f, 0.f, 0.f};
  f32x4 acc[8][4];
#pragma unroll
  for (int m = 0; m < 8; ++m)
#pragma unroll
    for (int n = 0; n < 4; ++n) acc[m][n] = fzero;

  const short* gA = eB + row0 * 2048;
  const short* gB = Xt + col0 * 2048;

  auto STAGE = [&](int kt, int isB, int h) {
    int ktc = kt < NT_K ? kt : NT_K - 1;  // clamp: keep vmcnt counts uniform
    const short* src = (isB ? gB : gA) + (h * 128) * 2048 + ktc * 64;
    int sbase = ((ktc & 1) << 15) + (isB << 14) + (h << 13);
#pragma unroll
    for (int p = 0; p < 2; ++p) {
      int c = p * 512 + tid;
      int r = c >> 3;
      int ke = ((((c & 7) << 4) ^ ((r & 7) << 4)) >> 1);
      gload_lds16(src + r * 2048 + ke,
                  lds + sbase + ((p * 512 + wid * 64) << 3));
    }
  };
  auto LDA = [&](int buf, int ks, int m) -> bf16x8 {
    int R = wr * 128 + m * 16 + lrow;
    int kb = ks * 64 + khi;
    return *(const bf16x8*)((const char*)lds + (buf << 16) + R * 128 +
                            (kb ^ ((R & 7) << 4)));
  };
  auto LDB = [&](int buf, int ks, int n) -> bf16x8 {
    int Rc = wc * 64 + n * 16 + lrow;
    int kb = ks * 64 + khi;
    return *(const bf16x8*)((const char*)lds + (buf << 16) + 32768 +
                            Rc * 128 + (kb ^ ((Rc & 7) << 4)));
  };

  // prologue: K-tile 0 (buf0) fully + K-tile 1 (buf1) A halves
  STAGE(0, 0, 0); STAGE(0, 0, 1); STAGE(0, 1, 0); STAGE(0, 1, 1);
  STAGE(1, 0, 0); STAGE(1, 0, 1);
  VMCNT4();  // first 8 loads (buf0) landed
  __builtin_amdgcn_sched_barrier(0);
  __builtin_amdgcn_s_barrier();

  bf16x8 fa0[8], fa1[8], fb0[4], fb1[4];

  for (int it = 0; it < NT_K / 2; ++it) {
    const int t0 = 2 * it, t1 = 2 * it + 1;
    // ph0: read t0/ks0 (12 reads); stage t1.B0; MFMA t0 ks0 nh0
#pragma unroll
    for (int m = 0; m < 8; ++m) fa0[m] = LDA(0, 0, m);
#pragma unroll
    for (int n = 0; n < 4; ++n) fb0[n] = LDB(0, 0, n);
    STAGE(t1, 1, 0);
    PHASE_MID();
    MM(fa0, fb0, 0);
    PHASE_END();
    // ph1: read t0/ks1; stage t1.B1; MFMA t0 ks0 nh1
#pragma unroll
    for (int m = 0; m < 8; ++m) fa1[m] = LDA(0, 1, m);
#pragma unroll
    for (int n = 0; n < 4; ++n) fb1[n] = LDB(0, 1, n);
    STAGE(t1, 1, 1);
    PHASE_MID();
    MM(fa0, fb0, 1);
    PHASE_END();
    // ph2: stage (t0+2).A0; MFMA t0 ks1 nh0
    STAGE(t0 + 2, 0, 0);
    PHASE_MID();
    MM(fa1, fb1, 0);
    PHASE_END();
    // ph3: stage (t0+2).A1; vmcnt(4) -> buf1 (t1) fully landed; MFMA t0 ks1 nh1
    STAGE(t0 + 2, 0, 1);
    VMCNT4();
    PHASE_MID();
    MM(fa1, fb1, 1);
    PHASE_END();
    // ph4: read t1/ks0; stage (t0+2).B0; MFMA t1 ks0 nh0
#pragma unroll
    for (int m = 0; m < 8; ++m) fa0[m] = LDA(1, 0, m);
#pragma unroll
    for (int n = 0; n < 4; ++n) fb0[n] = LDB(1, 0, n);
    STAGE(t0 + 2, 1, 0);
    PHASE_MID();
    MM(fa0, fb0, 0);
    PHASE_END();
    // ph5: read t1/ks1; stage (t0+2).B1; MFMA t1 ks0 nh1
#pragma unroll
    for (int m = 0; m < 8; ++m) fa1[m] = LDA(1, 1, m);
#pragma unroll
    for (int n = 0; n < 4; ++n) fb1[n] = LDB(1, 1, n);
    STAGE(t0 + 2, 1, 1);
    PHASE_MID();
    MM(fa0, fb0, 1);
    PHASE_END();
    // ph6: stage (t1+2).A0; MFMA t1 ks1 nh0
    STAGE(t1 + 2, 0, 0);
    PHASE_MID();
    MM(fa1, fb1, 0);
    PHASE_END();
    // ph7: stage (t1+2).A1; vmcnt(4) -> buf0 (t0+2) fully landed; MFMA t1 ks1 nh1
    STAGE(t1 + 2, 0, 1);
    VMCNT4();
    PHASE_MID();
    MM(fa1, fb1, 1);
    PHASE_END();
  }

  // epilogue: C/D frag col = lane&15, row = (lane>>4)*4 + reg
  const int rbase = row0 + wr * 128 + ((lane >> 4) << 2);
#pragma unroll
  for (int n = 0; n < 4; ++n) {
    int c = col0 + wc * 64 + n * 16 + lrow;
    int b = c >> 10;
    int d = (c & 1023) >> 1;
#pragma unroll
    for (int m = 0; m < 8; ++m) {
      f32x4 den;
#pragma unroll
      for (int r = 0; r < 4; ++r) den[r] = __shfl_xor(acc[m][n][r], 1);
      if ((lane & 1) == 0) {  // even lane: acc=num, partner holds den
#pragma unroll
        for (int r = 0; r < 4; ++r) {
          int i2 = rbase + m * 16 + r;
          int idx = (b * 2048 + i2) * 512 + d;
          out[idx] = h2f(sigq[idx]) * (acc[m][n][r] / den[r]);
        }
      }
    }
  }
}

// ---------------- launch ----------------
extern "C" void kernel_launch(void* const* d_in, const int* in_sizes, int n_in,
                              void* d_out, int out_size, void* d_ws, size_t ws_size,
                              hipStream_t stream) {
  const float* in = (const float*)d_in[0];
  const float* Wq = (const float*)d_in[1];
  const float* bq = (const float*)d_in[2];
  const float* Wk = (const float*)d_in[3];
  const float* bk = (const float*)d_in[4];
  const float* Wv = (const float*)d_in[5];
  const float* bv = (const float*)d_in[6];
  const float* pb = (const float*)d_in[7];
  float* out = (float*)d_out;

  char* ws = (char*)d_ws;
  short* Xt = (short*)ws;                              // 33,554,432 B
  short* eB = (short*)(ws + 33554432);                 //  8,388,608 B
  short* Ah = (short*)(ws + 41943040);                 // 16,777,216 B
  short* Wh = (short*)(ws + 58720256);                 //  1,572,864 B
  unsigned short* sigq = (unsigned short*)(ws + 60293120);  // 16,777,216 B

  (void)hipFuncSetAttribute((const void*)k_main8,
                            hipFuncAttributeMaxDynamicSharedMemorySize, 131072);

  k_conv_bf16<<<2048, 256, 0, stream>>>(in, Ah, MROWS * D_MODEL / 4);
  k_prep_w<<<3072, 256, 0, stream>>>(Wq, Wk, Wv, Wh);
  k_prep_eb<<<2048, 256, 0, stream>>>(pb, eB, N_SEQ * N_SEQ / 4);

  dim3 gp(128, 12);
  k_proj<<<gp, 256, 0, stream>>>(Ah, Wh, bq, bk, bv, sigq, Xt);

  k_main8<<<dim3(256), 512, 131072, stream>>>(eB, Xt, sigq, out);
}